// Round 1
// 95.571 us; speedup vs baseline: 1.2183x; 1.2183x over previous
//
#include <hip/hip_runtime.h>

// GaussianEM R5: two-dispatch, zero-atomic, zero-memset design.
//
// loss = sum_{c,d}(means[LAST][d]-mean_param[c][d])^2 + cov_sq_last(~1e-10, skipped)
//        + sum(cov_param^2)
//
// R4/R2 lessons: device-scope fences inside the kernel (release/acquire handoff,
// grid.sync) cost ~40 us of L2 cache maintenance against the 256MiB poison fill;
// the atomicAdd publish avoided that but still pays 128-way serialized atomics +
// arrival counter + fetch-add readback + a serial last-block tail, all after the
// parallel phase, plus a separate 268B memset dispatch to zero the accumulators.
//
// R5 removes all of it:
//  - K1 (128 blocks): each block PLAIN-STORES its partial {64 feature sums, count,
//    covsum} into a private ws slot -> no init needed (poisoned ws fully
//    overwritten), no atomics, no fence. Block 0 additionally computes the
//    data-independent terms colsum[d] = sum_c mean_param[c][d] and sum(mp^2),
//    overlapped with the other 127 blocks' work (algebraic hoist:
//    sum_{c,d}(m-P)^2 = C*sum m^2 - 2*sum m*colsum + sum P^2).
//  - K2 (1 block): reduces 128 slots (34 KB, L3-resident after K1's implicit
//    end-of-dispatch release) and does a 64-element dot product. Inter-kernel
//    visibility is stream-order guaranteed (safe under G16, unlike intra-kernel
//    cross-XCD handoff).
//
// ws layout (floats): slot b at [b*68]: [0..63]=sums, [64]=count, [65]=covsum.
//                     [128*68 + 0..63]=colsum, [128*68+64]=sum(mean_param^2).

#define DIM 64
#define NCLASSES 128
#define LAST (NCLASSES - 1)
#define NBLOCKS 128
#define BLOCK 512                      // 8 waves/block; 1024 waves total
#define NWAVES (NBLOCKS * 8)
#define SLOT 68                        // 66 used + pad to 16B multiple
#define COLBASE (NBLOCKS * SLOT)

__global__ __launch_bounds__(BLOCK) void gem_part(
    const float* __restrict__ inputs, const int* __restrict__ target,
    const float* __restrict__ mean_param, const float* __restrict__ cov_param,
    int n, int cov_n4, float* __restrict__ ws)
{
    const int tid  = threadIdx.x;
    const int lane = tid & 63;
    const int wib  = tid >> 6;                 // wave in block (0..7)
    const int b    = blockIdx.x;
    const int gwave = b * 8 + wib;             // 0..1023

    // ---- target scan: one int4 load per lane covers 256 samples per wave ----
    float acc = 0.f;
    int   cnt = 0;
    for (int base = gwave * 256; base < n; base += NWAVES * 256) {   // 1 iter at n=262144
        const int4 t4 = *(const int4*)(target + base + lane * 4);    // 16B coalesced
        unsigned long long m0 = __ballot(t4.x == LAST);
        unsigned long long m1 = __ballot(t4.y == LAST);
        unsigned long long m2 = __ballot(t4.z == LAST);
        unsigned long long m3 = __ballot(t4.w == LAST);
        cnt += __popcll(m0) + __popcll(m1) + __popcll(m2) + __popcll(m3);
        #pragma unroll
        for (int j = 0; j < 4; ++j) {
            unsigned long long m = (j == 0) ? m0 : (j == 1) ? m1 : (j == 2) ? m2 : m3;
            while (m) {
                int bit = __ffsll(m) - 1;
                m &= m - 1;
                acc += inputs[(size_t)(base + 4 * bit + j) * DIM + lane]; // lane = dim
            }
        }
    }

    // ---- sum(cov_param^2): 2 independent float4 loads per thread ----
    const float4* c4 = (const float4*)cov_param;
    float csum = 0.f;
    for (int i = b * BLOCK + tid; i < cov_n4; i += NBLOCKS * BLOCK) {
        float4 v = c4[i];
        csum += v.x * v.x + v.y * v.y + v.z * v.z + v.w * v.w;
    }
    for (int off = 32; off; off >>= 1) csum += __shfl_down(csum, off, 64);

    // ---- block 0 only: data-independent mean_param terms, overlapped ----
    float pcol = 0.f, psq = 0.f;
    if (b == 0) {
        #pragma unroll
        for (int k = 0; k < (NCLASSES * DIM) / BLOCK; ++k) {   // 16 coalesced loads
            float v = mean_param[tid + k * BLOCK];             // d = tid&63 fixed
            pcol += v;
            psq  += v * v;
        }
    }
    for (int off = 32; off; off >>= 1) psq += __shfl_down(psq, off, 64);

    __shared__ float sacc[8][DIM];
    __shared__ float scol[8][DIM];
    __shared__ float scov[8], spsq[8];
    __shared__ int   scnt[8];
    sacc[wib][lane] = acc;
    scol[wib][lane] = pcol;
    if (lane == 0) { scov[wib] = csum; scnt[wib] = cnt; spsq[wib] = psq; }
    __syncthreads();

    // ---- publish: plain coalesced stores to a private slot (no atomics) ----
    if (wib == 0) {
        float s = 0.f;
        #pragma unroll
        for (int w = 0; w < 8; ++w) s += sacc[w][lane];
        ws[b * SLOT + lane] = s;                       // 256B coalesced store
        if (b == 0) {
            float cs = 0.f;
            #pragma unroll
            for (int w = 0; w < 8; ++w) cs += scol[w][lane];
            ws[COLBASE + lane] = cs;
        }
    }
    if (tid == 0) {
        int   c  = 0;   float cv = 0.f, q = 0.f;
        #pragma unroll
        for (int w = 0; w < 8; ++w) { c += scnt[w]; cv += scov[w]; q += spsq[w]; }
        ws[b * SLOT + DIM]     = (float)c;
        ws[b * SLOT + DIM + 1] = cv;
        if (b == 0) ws[COLBASE + DIM] = q;
    }
}

__global__ __launch_bounds__(BLOCK) void gem_final(
    const float* __restrict__ ws, float* __restrict__ out)
{
    const int tid  = threadIdx.x;
    const int lane = tid & 63;
    const int g    = tid >> 6;                 // 0..7

    // reduce 128 slots: thread (g,lane) sums blocks {g, g+8, ..., g+120} at dim=lane
    float s = 0.f;
    #pragma unroll
    for (int j = 0; j < NBLOCKS / 8; ++j)
        s += ws[(g + 8 * j) * SLOT + lane];    // 256B coalesced per wave

    // counts / covsums: threads 0..127 each pick up one slot's scalars
    float c = 0.f, cv = 0.f;
    if (tid < NBLOCKS) { c = ws[tid * SLOT + DIM]; cv = ws[tid * SLOT + DIM + 1]; }
    for (int off = 32; off; off >>= 1) {
        c  += __shfl_down(c,  off, 64);
        cv += __shfl_down(cv, off, 64);
    }

    __shared__ float red[8][DIM];
    __shared__ float scc[2][2];
    red[g][lane] = s;
    if (tid < NBLOCKS && lane == 0) { scc[g][0] = c; scc[g][1] = cv; }
    __syncthreads();

    if (tid < DIM) {                           // wave 0 finishes alone
        float tot = 0.f;
        #pragma unroll
        for (int w = 0; w < 8; ++w) tot += red[w][tid];
        const float count = scc[0][0] + scc[1][0];
        const float covs  = scc[0][1] + scc[1][1];
        const float mean  = tot / count;
        const float col   = ws[COLBASE + tid];
        // sum_{c,d}(mean_d - P_{c,d})^2 = C*sum mean^2 - 2*sum mean*colsum + sum P^2
        float d = (float)NCLASSES * mean * mean - 2.f * mean * col;
        for (int off = 32; off; off >>= 1) d += __shfl_down(d, off, 64);
        if (tid == 0) out[0] = d + covs + ws[COLBASE + DIM];
    }
}

extern "C" void kernel_launch(void* const* d_in, const int* in_sizes, int n_in,
                              void* d_out, int out_size, void* d_ws, size_t ws_size,
                              hipStream_t stream) {
    const float* inputs     = (const float*)d_in[0];
    const int*   target     = (const int*)d_in[1];
    const float* mean_param = (const float*)d_in[2];
    const float* cov_param  = (const float*)d_in[3];
    float* out = (float*)d_out;
    float* ws  = (float*)d_ws;

    const int n     = in_sizes[0] / DIM;   // 262144
    const int cov_n = in_sizes[3];         // 128*64*64 = 524288

    // no memset: every ws location K2 reads is plain-stored by K1 this launch
    gem_part<<<NBLOCKS, BLOCK, 0, stream>>>(inputs, target, mean_param, cov_param,
                                            n, cov_n / 4, ws);
    gem_final<<<1, BLOCK, 0, stream>>>(ws, out);
}